// Round 9
// baseline (181.395 us; speedup 1.0000x reference)
//
#include <hip/hip_runtime.h>
#include <hip/hip_fp16.h>

#define CC 256   // input channels
#define OO 256   // output channels
#define HH 64
#define WW 64
#define HWN 4096 // H*W
#define MPB 64   // pixels per block
#define NPB 128  // outputs per block
#define KCH 128  // c-chunk for weight staging
#define VST 264  // val_lds row stride (halfs)
#define WST 136  // w_lds row stride (halfs)

typedef _Float16 half8 __attribute__((ext_vector_type(8)));
typedef _Float16 half2v __attribute__((ext_vector_type(2)));
typedef float f32x4 __attribute__((ext_vector_type(4)));

__device__ __forceinline__ half2v u2h(unsigned u) {
  half2v h; __builtin_memcpy(&h, &u, 4); return h;
}
__device__ __forceinline__ unsigned h2u(half2v h) {
  unsigned u; __builtin_memcpy(&u, &h, 4); return u;
}
__device__ __forceinline__ unsigned short f2h(float f) {
  _Float16 h = (_Float16)f;
  unsigned short us; __builtin_memcpy(&us, &h, 2);
  return us;
}
__device__ __forceinline__ unsigned dupu(unsigned short us) {
  return ((unsigned)us << 16) | us;
}
__device__ __forceinline__ unsigned pk2(float a, float b) {
  half2v h = {(_Float16)a, (_Float16)b};
  return h2u(h);
}

// ---------- fused prep: x [N,C,H,W] f32 -> xt [N,HW,C] fp16 ; w -> wt [9][O][C] fp16 ----------
__global__ __launch_bounds__(256) void prep_kernel(
    const float* __restrict__ x, const float* __restrict__ w,
    _Float16* __restrict__ xt, _Float16* __restrict__ wt) {
  __shared__ float tile[64][65];
  const int bid = blockIdx.x;
  const int tid = threadIdx.x;
  if (bid < 1024) {
    const int n  = bid >> 8;
    const int c0 = ((bid >> 6) & 3) * 64;
    const int s0 = (bid & 63) * 64;
    {
      int r  = tid >> 2;
      int sc = (tid & 3) * 16;
      const float* xp = x + ((size_t)(n * CC + c0 + r)) * HWN + s0 + sc;
      *(float4*)&tile[r][sc]      = *(const float4*)(xp);
      *(float4*)&tile[r][sc + 4]  = *(const float4*)(xp + 4);
      *(float4*)&tile[r][sc + 8]  = *(const float4*)(xp + 8);
      *(float4*)&tile[r][sc + 12] = *(const float4*)(xp + 12);
    }
    __syncthreads();
    {
      int s  = tid >> 2;
      int cg = (tid & 3) * 16;
      uint4 u0, u1;
      u0.x = pk2(tile[cg + 0][s],  tile[cg + 1][s]);
      u0.y = pk2(tile[cg + 2][s],  tile[cg + 3][s]);
      u0.z = pk2(tile[cg + 4][s],  tile[cg + 5][s]);
      u0.w = pk2(tile[cg + 6][s],  tile[cg + 7][s]);
      u1.x = pk2(tile[cg + 8][s],  tile[cg + 9][s]);
      u1.y = pk2(tile[cg + 10][s], tile[cg + 11][s]);
      u1.z = pk2(tile[cg + 12][s], tile[cg + 13][s]);
      u1.w = pk2(tile[cg + 14][s], tile[cg + 15][s]);
      _Float16* op = xt + ((size_t)(n * HWN + s0 + s)) * CC + c0 + cg;
      *(uint4*)(op)     = u0;
      *(uint4*)(op + 8) = u1;
    }
  } else {
    int e = (bid - 1024) * 256 + tid;   // 0 .. 589823
    int k = e >> 16;
    int o = (e >> 8) & 255;
    int c = e & 255;
    wt[e] = (_Float16)w[((size_t)o * CC + c) * 9 + k];
  }
}

// ---------------- fused deform-sample (fp16 packed) + MFMA GEMM, latency-batched ----------------
// grid 512 x 256 thr. Block: 64 px x 128 o. XCD-aware decode (XCD ~ bx%8):
//   nb = (bx&7)>>1 (one image per XCD), o-half = bx&1, pixel group = bx>>3.
__global__ __launch_bounds__(256, 2) void deform_mfma_kernel(
    const _Float16* __restrict__ xt,   // [4][4096][256] fp16
    const _Float16* __restrict__ wt,   // [9][256][256] fp16 ([k][o][c])
    const float* __restrict__ off,
    float* __restrict__ out) {
  __shared__ __align__(16) _Float16 val_lds[MPB * VST];   // 33792 B [p][c]
  __shared__ __align__(16) _Float16 w_lds[NPB * WST];     // 34816 B [o][c-in-chunk]
  __shared__ ushort4 s_po[MPB * 9];   // clamped flat corner row offsets
  __shared__ ushort4 s_pw[MPB * 9];   // fp16 bilinear weights

  const int tid  = threadIdx.x;
  const int lane = tid & 63;
  const int wv   = tid >> 6;
  const int n15  = lane & 15;
  const int quad = lane >> 4;

  const int bx    = blockIdx.x;
  const int nb    = (bx & 7) >> 1;          // image: constant per XCD
  const int hw0   = (bx >> 3) * MPB;        // pixel group within image
  const int obase = (bx & 1) * NPB;         // output half

  // ---- precompute per-(pixel,tap) sampling params ----
  for (int e = tid; e < MPB * 9; e += 256) {
    int p = e / 9;
    int k = e - p * 9;
    int hw = hw0 + p;
    int h = hw >> 6, w = hw & 63;
    size_t ob = ((size_t)(nb * HWN + hw)) * 18 + 2 * k;
    float2 d = *(const float2*)(off + ob);
    float py = (float)(h + k / 3 - 1) + d.x;
    float px = (float)(w + k % 3 - 1) + d.y;
    float fy = floorf(py), fx = floorf(px);
    int iy = (int)fy, ix = (int)fx;
    float wy = py - fy, wx = px - fx;
    float my0 = ((unsigned)iy       < (unsigned)HH) ? 1.f : 0.f;
    float my1 = ((unsigned)(iy + 1) < (unsigned)HH) ? 1.f : 0.f;
    float mx0 = ((unsigned)ix       < (unsigned)WW) ? 1.f : 0.f;
    float mx1 = ((unsigned)(ix + 1) < (unsigned)WW) ? 1.f : 0.f;
    int iy0 = min(max(iy, 0), HH - 1), iy1 = min(max(iy + 1, 0), HH - 1);
    int ix0 = min(max(ix, 0), WW - 1), ix1 = min(max(ix + 1, 0), WW - 1);
    s_po[e] = make_ushort4((unsigned short)(iy0 * WW + ix0),
                           (unsigned short)(iy0 * WW + ix1),
                           (unsigned short)(iy1 * WW + ix0),
                           (unsigned short)(iy1 * WW + ix1));
    s_pw[e] = make_ushort4(f2h((1.f - wy) * (1.f - wx) * my0 * mx0),
                           f2h((1.f - wy) * wx         * my0 * mx1),
                           f2h(wy         * (1.f - wx) * my1 * mx0),
                           f2h(wy         * wx         * my1 * mx1));
  }
  __syncthreads();   // params visible (needed before prologue/tap-0 load issue)

  f32x4 acc[4][2];
#pragma unroll
  for (int a = 0; a < 4; ++a)
#pragma unroll
    for (int b = 0; b < 2; ++b) acc[a][b] = (f32x4){0.f, 0.f, 0.f, 0.f};

  const _Float16* xb = xt + (size_t)nb * HWN * CC;
  const int j  = lane & 31;            // channel chunk j*8..j*8+7
  const int ph = lane >> 5;            // which pixel of the pair
  const int q    = tid & 3;            // B-staging column group
  const int orow = tid >> 2;           // B-staging row 0..63

  // ---- register-pipelined B staging helpers ----
  uint4 breg[8];
  auto bld = [&](int kk, int cc) {
#pragma unroll
    for (int rr = 0; rr < 2; ++rr) {
      const uint4* src = (const uint4*)(wt + ((size_t)(kk * OO + obase + rr * 64 + orow)) * CC +
                                        cc * KCH + q * 32);
#pragma unroll
      for (int jj = 0; jj < 4; ++jj) breg[rr * 4 + jj] = src[jj];
    }
  };

  bld(0, 0);   // prologue: first chunk in flight

  for (int k = 0; k < 9; ++k) {
    // ---- issue ALL 32 corner loads for tap k (in flight across the barrier) ----
    uint4 ld[8][4];
#pragma unroll
    for (int i = 0; i < 8; ++i) {
      int p = i * 8 + wv * 2 + ph;
      ushort4 o4 = s_po[p * 9 + k];
      const _Float16* cb = xb + (size_t)j * 8;
      ld[i][0] = *(const uint4*)(cb + (size_t)o4.x * CC);
      ld[i][1] = *(const uint4*)(cb + (size_t)o4.y * CC);
      ld[i][2] = *(const uint4*)(cb + (size_t)o4.z * CC);
      ld[i][3] = *(const uint4*)(cb + (size_t)o4.w * CC);
    }

    __syncthreads();   // prev tap A-reads of val_lds done

    // ---- combine + write val_lds (fp16 packed math) ----
#pragma unroll
    for (int i = 0; i < 8; ++i) {
      int p = i * 8 + wv * 2 + ph;
      ushort4 hw4 = s_pw[p * 9 + k];
      half2v w00 = u2h(dupu(hw4.x)), w01 = u2h(dupu(hw4.y));
      half2v w10 = u2h(dupu(hw4.z)), w11 = u2h(dupu(hw4.w));
      uint4 r;
      r.x = h2u(u2h(ld[i][0].x) * w00 + u2h(ld[i][1].x) * w01 + u2h(ld[i][2].x) * w10 + u2h(ld[i][3].x) * w11);
      r.y = h2u(u2h(ld[i][0].y) * w00 + u2h(ld[i][1].y) * w01 + u2h(ld[i][2].y) * w10 + u2h(ld[i][3].y) * w11);
      r.z = h2u(u2h(ld[i][0].z) * w00 + u2h(ld[i][1].z) * w01 + u2h(ld[i][2].z) * w10 + u2h(ld[i][3].z) * w11);
      r.w = h2u(u2h(ld[i][0].w) * w00 + u2h(ld[i][1].w) * w01 + u2h(ld[i][2].w) * w10 + u2h(ld[i][3].w) * w11);
      *(uint4*)(val_lds + p * VST + j * 8) = r;   // consecutive 16B per half-wave
    }

    // ---- GEMM tap k over two 128-channel chunks, B pipelined through breg ----
    for (int cc = 0; cc < CC / KCH; ++cc) {
      __syncthreads();   // prev chunk B-reads done -> w_lds writable
      {
        // store staged chunk from registers
#pragma unroll
        for (int rr = 0; rr < 2; ++rr) {
          uint4* dst = (uint4*)(w_lds + (rr * 64 + orow) * WST + q * 32);
#pragma unroll
          for (int jj = 0; jj < 4; ++jj) dst[jj] = breg[rr * 4 + jj];
        }
        // issue next chunk's loads (hide under MFMA below)
        int nk = (cc == 0) ? k : k + 1;
        int ncc = cc ^ 1;
        if (nk < 9) bld(nk, ncc);
      }
      __syncthreads();   // w_lds staged; also orders val_lds writes before A-reads (cc==0)
#pragma unroll
      for (int ks = 0; ks < 4; ++ks) {
        int cbase = cc * KCH + ks * 32;
        half8 afr[4], bfr[2];
#pragma unroll
        for (int mt = 0; mt < 4; ++mt)
          afr[mt] = *(const half8*)(val_lds + (mt * 16 + n15) * VST + cbase + quad * 8);
#pragma unroll
        for (int nt = 0; nt < 2; ++nt)
          bfr[nt] = *(const half8*)(w_lds + (wv * 32 + nt * 16 + n15) * WST + ks * 32 + quad * 8);
#pragma unroll
        for (int mt = 0; mt < 4; ++mt)
#pragma unroll
          for (int nt = 0; nt < 2; ++nt)
            acc[mt][nt] = __builtin_amdgcn_mfma_f32_16x16x32_f16(
                afr[mt], bfr[nt], acc[mt][nt], 0, 0, 0);
      }
    }
  }

  // ---- epilogue: D: col=lane&15 -> o, row=quad*4+reg -> pixel ----
#pragma unroll
  for (int mt = 0; mt < 4; ++mt)
#pragma unroll
    for (int nt = 0; nt < 2; ++nt) {
      int o  = obase + wv * 32 + nt * 16 + n15;
      int px = hw0 + mt * 16 + quad * 4;
      *(f32x4*)(out + ((size_t)nb * OO + o) * HWN + px) = acc[mt][nt];
    }
}

extern "C" void kernel_launch(void* const* d_in, const int* in_sizes, int n_in,
                              void* d_out, int out_size, void* d_ws, size_t ws_size,
                              hipStream_t stream) {
  const float* x   = (const float*)d_in[0];   // [4,256,64,64]
  const float* off = (const float*)d_in[1];   // [4,4096,18]
  const float* w   = (const float*)d_in[2];   // [256,256,3,3]
  float* out = (float*)d_out;                 // [4,256,64,64]

  _Float16* wt = (_Float16*)d_ws;             // 589824 fp16
  _Float16* xt = wt + 589824;                 // 4194304 fp16

  prep_kernel<<<1024 + 2304, 256, 0, stream>>>(x, w, xt, wt);
  deform_mfma_kernel<<<(4 * HWN / MPB) * (OO / NPB), 256, 0, stream>>>(xt, wt, off, out);
}

// Round 10
// 153.653 us; speedup vs baseline: 1.1805x; 1.1805x over previous
//
#include <hip/hip_runtime.h>
#include <hip/hip_fp16.h>

#define CC 256   // input channels
#define OO 256   // output channels
#define HH 64
#define WW 64
#define HWN 4096 // H*W
#define MPB 64   // pixels per block
#define KCH 64   // c-chunk for weight staging
#define VST 264  // val_lds row stride (halfs)
#define WST 72   // w_lds row stride (halfs)

typedef _Float16 half8 __attribute__((ext_vector_type(8)));
typedef _Float16 half2v __attribute__((ext_vector_type(2)));
typedef float f32x4 __attribute__((ext_vector_type(4)));

__device__ __forceinline__ half2v u2h(unsigned u) {
  half2v h; __builtin_memcpy(&h, &u, 4); return h;
}
__device__ __forceinline__ unsigned h2u(half2v h) {
  unsigned u; __builtin_memcpy(&u, &h, 4); return u;
}
__device__ __forceinline__ unsigned short f2h(float f) {
  _Float16 h = (_Float16)f;
  unsigned short us; __builtin_memcpy(&us, &h, 2);
  return us;
}
__device__ __forceinline__ unsigned dupu(unsigned short us) {
  return ((unsigned)us << 16) | us;
}
__device__ __forceinline__ unsigned pk2(float a, float b) {
  half2v h = {(_Float16)a, (_Float16)b};
  return h2u(h);
}

// ---------- fused prep: x [N,C,H,W] f32 -> xt [N,HW,C] fp16 ; w -> wt [9][O][C] fp16 ----------
__global__ __launch_bounds__(256) void prep_kernel(
    const float* __restrict__ x, const float* __restrict__ w,
    _Float16* __restrict__ xt, _Float16* __restrict__ wt) {
  __shared__ float tile[64][65];
  const int bid = blockIdx.x;
  const int tid = threadIdx.x;
  if (bid < 1024) {
    const int n  = bid >> 8;
    const int c0 = ((bid >> 6) & 3) * 64;
    const int s0 = (bid & 63) * 64;
    {
      int r  = tid >> 2;
      int sc = (tid & 3) * 16;
      const float* xp = x + ((size_t)(n * CC + c0 + r)) * HWN + s0 + sc;
      *(float4*)&tile[r][sc]      = *(const float4*)(xp);
      *(float4*)&tile[r][sc + 4]  = *(const float4*)(xp + 4);
      *(float4*)&tile[r][sc + 8]  = *(const float4*)(xp + 8);
      *(float4*)&tile[r][sc + 12] = *(const float4*)(xp + 12);
    }
    __syncthreads();
    {
      int s  = tid >> 2;
      int cg = (tid & 3) * 16;
      uint4 u0, u1;
      u0.x = pk2(tile[cg + 0][s],  tile[cg + 1][s]);
      u0.y = pk2(tile[cg + 2][s],  tile[cg + 3][s]);
      u0.z = pk2(tile[cg + 4][s],  tile[cg + 5][s]);
      u0.w = pk2(tile[cg + 6][s],  tile[cg + 7][s]);
      u1.x = pk2(tile[cg + 8][s],  tile[cg + 9][s]);
      u1.y = pk2(tile[cg + 10][s], tile[cg + 11][s]);
      u1.z = pk2(tile[cg + 12][s], tile[cg + 13][s]);
      u1.w = pk2(tile[cg + 14][s], tile[cg + 15][s]);
      _Float16* op = xt + ((size_t)(n * HWN + s0 + s)) * CC + c0 + cg;
      *(uint4*)(op)     = u0;
      *(uint4*)(op + 8) = u1;
    }
  } else {
    int e = (bid - 1024) * 256 + tid;   // 0 .. 589823
    int k = e >> 16;
    int o = (e >> 8) & 255;
    int c = e & 255;
    wt[e] = (_Float16)w[((size_t)o * CC + c) * 9 + k];
  }
}

// ---------------- fused deform-sample (fp16 packed) + MFMA GEMM ----------------
// grid 256 x 256 thr. Block: 64 px x ALL 256 o (no o-split -> sampling done once).
// XCD-aware decode (XCD ~ bx%8): nb = (bx&7)>>1 (one image per XCD pair),
//   pixel group = (bx>>3)*2 + (bx&1)  (the two XCDs of an image split even/odd groups).
// Wave wv owns outputs wv*64..wv*64+63 (4 n-tiles), all 4 m-tiles: acc[4][4].
__global__ __launch_bounds__(256, 2) void deform_mfma_kernel(
    const _Float16* __restrict__ xt,   // [4][4096][256] fp16
    const _Float16* __restrict__ wt,   // [9][256][256] fp16 ([k][o][c])
    const float* __restrict__ off,
    float* __restrict__ out) {
  __shared__ __align__(16) _Float16 val_lds[MPB * VST];   // 33792 B [p][c]
  __shared__ __align__(16) _Float16 w_lds[OO * WST];      // 36864 B [o][c-in-chunk]
  __shared__ ushort4 s_po[MPB * 9];   // clamped flat corner row offsets (4.5 KB)
  __shared__ ushort4 s_pw[MPB * 9];   // fp16 bilinear weights (4.5 KB)

  const int tid  = threadIdx.x;
  const int lane = tid & 63;
  const int wv   = tid >> 6;
  const int n15  = lane & 15;
  const int quad = lane >> 4;

  const int bx  = blockIdx.x;
  const int nb  = (bx & 7) >> 1;                     // image: constant per XCD
  const int hw0 = ((bx >> 3) * 2 + (bx & 1)) * MPB;  // pixel group within image

  // ---- precompute per-(pixel,tap) sampling params ----
  for (int e = tid; e < MPB * 9; e += 256) {
    int p = e / 9;
    int k = e - p * 9;
    int hw = hw0 + p;
    int h = hw >> 6, w = hw & 63;
    size_t ob = ((size_t)(nb * HWN + hw)) * 18 + 2 * k;
    float2 d = *(const float2*)(off + ob);
    float py = (float)(h + k / 3 - 1) + d.x;
    float px = (float)(w + k % 3 - 1) + d.y;
    float fy = floorf(py), fx = floorf(px);
    int iy = (int)fy, ix = (int)fx;
    float wy = py - fy, wx = px - fx;
    float my0 = ((unsigned)iy       < (unsigned)HH) ? 1.f : 0.f;
    float my1 = ((unsigned)(iy + 1) < (unsigned)HH) ? 1.f : 0.f;
    float mx0 = ((unsigned)ix       < (unsigned)WW) ? 1.f : 0.f;
    float mx1 = ((unsigned)(ix + 1) < (unsigned)WW) ? 1.f : 0.f;
    int iy0 = min(max(iy, 0), HH - 1), iy1 = min(max(iy + 1, 0), HH - 1);
    int ix0 = min(max(ix, 0), WW - 1), ix1 = min(max(ix + 1, 0), WW - 1);
    s_po[e] = make_ushort4((unsigned short)(iy0 * WW + ix0),
                           (unsigned short)(iy0 * WW + ix1),
                           (unsigned short)(iy1 * WW + ix0),
                           (unsigned short)(iy1 * WW + ix1));
    s_pw[e] = make_ushort4(f2h((1.f - wy) * (1.f - wx) * my0 * mx0),
                           f2h((1.f - wy) * wx         * my0 * mx1),
                           f2h(wy         * (1.f - wx) * my1 * mx0),
                           f2h(wy         * wx         * my1 * mx1));
  }

  f32x4 acc[4][4];
#pragma unroll
  for (int a = 0; a < 4; ++a)
#pragma unroll
    for (int b = 0; b < 4; ++b) acc[a][b] = (f32x4){0.f, 0.f, 0.f, 0.f};

  const _Float16* xb = xt + (size_t)nb * HWN * CC;
  const int j  = lane & 31;            // channel chunk j*8..j*8+7
  const int ph = lane >> 5;            // which pixel of the pair

  for (int k = 0; k < 9; ++k) {
    __syncthreads();   // prev tap A-reads done; (k==0) params visible

    // ---- sample tap k: 2 pixels per wave-iter, contiguous 512B row loads (R7-proven) ----
#pragma unroll
    for (int i = 0; i < 8; ++i) {
      int p = i * 8 + wv * 2 + ph;
      int idx = p * 9 + k;
      ushort4 o4 = s_po[idx];
      ushort4 hw4 = s_pw[idx];
      half2v w00 = u2h(dupu(hw4.x)), w01 = u2h(dupu(hw4.y));
      half2v w10 = u2h(dupu(hw4.z)), w11 = u2h(dupu(hw4.w));
      const _Float16* cb = xb + (size_t)j * 8;
      uint4 v00 = *(const uint4*)(cb + (size_t)o4.x * CC);
      uint4 v01 = *(const uint4*)(cb + (size_t)o4.y * CC);
      uint4 v10 = *(const uint4*)(cb + (size_t)o4.z * CC);
      uint4 v11 = *(const uint4*)(cb + (size_t)o4.w * CC);
      uint4 r;
      r.x = h2u(u2h(v00.x) * w00 + u2h(v01.x) * w01 + u2h(v10.x) * w10 + u2h(v11.x) * w11);
      r.y = h2u(u2h(v00.y) * w00 + u2h(v01.y) * w01 + u2h(v10.y) * w10 + u2h(v11.y) * w11);
      r.z = h2u(u2h(v00.z) * w00 + u2h(v01.z) * w01 + u2h(v10.z) * w10 + u2h(v11.z) * w11);
      r.w = h2u(u2h(v00.w) * w00 + u2h(v01.w) * w01 + u2h(v10.w) * w10 + u2h(v11.w) * w11);
      *(uint4*)(val_lds + p * VST + j * 8) = r;   // consecutive 16B per half-wave
    }

    // ---- GEMM tap k over four 64-channel chunks ----
    for (int cc = 0; cc < CC / KCH; ++cc) {
      __syncthreads();   // prev chunk B-reads done
      {
        // stage 256 o x 64 c = 32 KB: thread tid copies its full row (8 x uint4)
        const uint4* src = (const uint4*)(wt + ((size_t)(k * OO + tid)) * CC + cc * KCH);
        uint4* dst = (uint4*)(w_lds + tid * WST);
#pragma unroll
        for (int jj = 0; jj < 8; ++jj) dst[jj] = src[jj];
      }
      __syncthreads();   // w_lds staged; also orders val_lds writes before A-reads (cc==0)
#pragma unroll
      for (int ks = 0; ks < 2; ++ks) {
        int cbase = cc * KCH + ks * 32;
        half8 afr[4], bfr[4];
#pragma unroll
        for (int mt = 0; mt < 4; ++mt)
          afr[mt] = *(const half8*)(val_lds + (mt * 16 + n15) * VST + cbase + quad * 8);
#pragma unroll
        for (int nt = 0; nt < 4; ++nt)
          bfr[nt] = *(const half8*)(w_lds + (wv * 64 + nt * 16 + n15) * WST + ks * 32 + quad * 8);
#pragma unroll
        for (int mt = 0; mt < 4; ++mt)
#pragma unroll
          for (int nt = 0; nt < 4; ++nt)
            acc[mt][nt] = __builtin_amdgcn_mfma_f32_16x16x32_f16(
                afr[mt], bfr[nt], acc[mt][nt], 0, 0, 0);
      }
    }
  }

  // ---- epilogue: D: col=lane&15 -> o, row=quad*4+reg -> pixel ----
#pragma unroll
  for (int mt = 0; mt < 4; ++mt)
#pragma unroll
    for (int nt = 0; nt < 4; ++nt) {
      int o  = wv * 64 + nt * 16 + n15;
      int px = hw0 + mt * 16 + quad * 4;
      *(f32x4*)(out + ((size_t)nb * OO + o) * HWN + px) = acc[mt][nt];
    }
}

extern "C" void kernel_launch(void* const* d_in, const int* in_sizes, int n_in,
                              void* d_out, int out_size, void* d_ws, size_t ws_size,
                              hipStream_t stream) {
  const float* x   = (const float*)d_in[0];   // [4,256,64,64]
  const float* off = (const float*)d_in[1];   // [4,4096,18]
  const float* w   = (const float*)d_in[2];   // [256,256,3,3]
  float* out = (float*)d_out;                 // [4,256,64,64]

  _Float16* wt = (_Float16*)d_ws;             // 589824 fp16
  _Float16* xt = wt + 589824;                 // 4194304 fp16

  prep_kernel<<<1024 + 2304, 256, 0, stream>>>(x, w, xt, wt);
  deform_mfma_kernel<<<4 * HWN / MPB, 256, 0, stream>>>(xt, wt, off, out);
}

// Round 12
// 132.958 us; speedup vs baseline: 1.3643x; 1.1557x over previous
//
#include <hip/hip_runtime.h>
#include <hip/hip_fp16.h>

#define CC 256   // input channels
#define OO 256   // output channels
#define HH 64
#define WW 64
#define HWN 4096 // H*W
#define MPB 64   // pixels per block
#define KCH 64   // c-chunk for weight staging
#define VST 264  // val_lds row stride (halfs)
#define WST 72   // w_lds row stride (halfs)

typedef _Float16 half8 __attribute__((ext_vector_type(8)));
typedef _Float16 half2v __attribute__((ext_vector_type(2)));
typedef float f32x4 __attribute__((ext_vector_type(4)));

__device__ __forceinline__ half2v u2h(unsigned u) {
  half2v h; __builtin_memcpy(&h, &u, 4); return h;
}
__device__ __forceinline__ unsigned h2u(half2v h) {
  unsigned u; __builtin_memcpy(&u, &h, 4); return u;
}
__device__ __forceinline__ unsigned short f2h(float f) {
  _Float16 h = (_Float16)f;
  unsigned short us; __builtin_memcpy(&us, &h, 2);
  return us;
}
__device__ __forceinline__ unsigned dupu(unsigned short us) {
  return ((unsigned)us << 16) | us;
}
__device__ __forceinline__ unsigned pk2(float a, float b) {
  half2v h = {(_Float16)a, (_Float16)b};
  return h2u(h);
}

// ---------- fused prep: x [N,C,H,W] f32 -> xt [N,HW,C] fp16 ; w -> wt [9][O][C] fp16 ----------
__global__ __launch_bounds__(256) void prep_kernel(
    const float* __restrict__ x, const float* __restrict__ w,
    _Float16* __restrict__ xt, _Float16* __restrict__ wt) {
  __shared__ float tile[64][65];
  const int bid = blockIdx.x;
  const int tid = threadIdx.x;
  if (bid < 1024) {
    const int n  = bid >> 8;
    const int c0 = ((bid >> 6) & 3) * 64;
    const int s0 = (bid & 63) * 64;
    {
      int r  = tid >> 2;
      int sc = (tid & 3) * 16;
      const float* xp = x + ((size_t)(n * CC + c0 + r)) * HWN + s0 + sc;
      *(float4*)&tile[r][sc]      = *(const float4*)(xp);
      *(float4*)&tile[r][sc + 4]  = *(const float4*)(xp + 4);
      *(float4*)&tile[r][sc + 8]  = *(const float4*)(xp + 8);
      *(float4*)&tile[r][sc + 12] = *(const float4*)(xp + 12);
    }
    __syncthreads();
    {
      int s  = tid >> 2;
      int cg = (tid & 3) * 16;
      uint4 u0, u1;
      u0.x = pk2(tile[cg + 0][s],  tile[cg + 1][s]);
      u0.y = pk2(tile[cg + 2][s],  tile[cg + 3][s]);
      u0.z = pk2(tile[cg + 4][s],  tile[cg + 5][s]);
      u0.w = pk2(tile[cg + 6][s],  tile[cg + 7][s]);
      u1.x = pk2(tile[cg + 8][s],  tile[cg + 9][s]);
      u1.y = pk2(tile[cg + 10][s], tile[cg + 11][s]);
      u1.z = pk2(tile[cg + 12][s], tile[cg + 13][s]);
      u1.w = pk2(tile[cg + 14][s], tile[cg + 15][s]);
      _Float16* op = xt + ((size_t)(n * HWN + s0 + s)) * CC + c0 + cg;
      *(uint4*)(op)     = u0;
      *(uint4*)(op + 8) = u1;
    }
  } else {
    int e = (bid - 1024) * 256 + tid;   // 0 .. 589823
    int k = e >> 16;
    int o = (e >> 8) & 255;
    int c = e & 255;
    wt[e] = (_Float16)w[((size_t)o * CC + c) * 9 + k];
  }
}

// ---------------- fused deform-sample (fp16 packed) + MFMA GEMM ----------------
// grid 256 x 512 thr (8 waves). Block: 64 px x ALL 256 o (sampling done exactly once).
// XCD-aware decode (XCD ~ bx%8): nb = (bx&7)>>1, pixel group = (bx>>3)*2 + (bx&1).
// Wave wv (0..7) owns outputs wv*32..wv*32+31 (2 n-tiles), all 4 m-tiles: acc[4][2].
__global__ __launch_bounds__(512, 1) void deform_mfma_kernel(
    const _Float16* __restrict__ xt,   // [4][4096][256] fp16
    const _Float16* __restrict__ wt,   // [9][256][256] fp16 ([k][o][c])
    const float* __restrict__ off,
    float* __restrict__ out) {
  __shared__ __align__(16) _Float16 val_lds[MPB * VST];   // 33792 B [p][c]
  __shared__ __align__(16) _Float16 w_lds[OO * WST];      // 36864 B [o][c-in-chunk]
  __shared__ ushort4 s_po[MPB * 9];   // clamped flat corner row offsets (4.5 KB)
  __shared__ ushort4 s_pw[MPB * 9];   // fp16 bilinear weights (4.5 KB)

  const int tid  = threadIdx.x;
  const int lane = tid & 63;
  const int wv   = tid >> 6;          // 0..7
  const int n15  = lane & 15;
  const int quad = lane >> 4;

  const int bx  = blockIdx.x;
  const int nb  = (bx & 7) >> 1;                     // image: constant per XCD
  const int hw0 = ((bx >> 3) * 2 + (bx & 1)) * MPB;  // pixel group within image

  // ---- precompute per-(pixel,tap) sampling params ----
  for (int e = tid; e < MPB * 9; e += 512) {
    int p = e / 9;
    int k = e - p * 9;
    int hw = hw0 + p;
    int h = hw >> 6, w = hw & 63;
    size_t ob = ((size_t)(nb * HWN + hw)) * 18 + 2 * k;
    float2 d = *(const float2*)(off + ob);
    float py = (float)(h + k / 3 - 1) + d.x;
    float px = (float)(w + k % 3 - 1) + d.y;
    float fy = floorf(py), fx = floorf(px);
    int iy = (int)fy, ix = (int)fx;
    float wy = py - fy, wx = px - fx;
    float my0 = ((unsigned)iy       < (unsigned)HH) ? 1.f : 0.f;
    float my1 = ((unsigned)(iy + 1) < (unsigned)HH) ? 1.f : 0.f;
    float mx0 = ((unsigned)ix       < (unsigned)WW) ? 1.f : 0.f;
    float mx1 = ((unsigned)(ix + 1) < (unsigned)WW) ? 1.f : 0.f;
    int iy0 = min(max(iy, 0), HH - 1), iy1 = min(max(iy + 1, 0), HH - 1);
    int ix0 = min(max(ix, 0), WW - 1), ix1 = min(max(ix + 1, 0), WW - 1);
    s_po[e] = make_ushort4((unsigned short)(iy0 * WW + ix0),
                           (unsigned short)(iy0 * WW + ix1),
                           (unsigned short)(iy1 * WW + ix0),
                           (unsigned short)(iy1 * WW + ix1));
    s_pw[e] = make_ushort4(f2h((1.f - wy) * (1.f - wx) * my0 * mx0),
                           f2h((1.f - wy) * wx         * my0 * mx1),
                           f2h(wy         * (1.f - wx) * my1 * mx0),
                           f2h(wy         * wx         * my1 * mx1));
  }

  f32x4 acc[4][2];
#pragma unroll
  for (int a = 0; a < 4; ++a)
#pragma unroll
    for (int b = 0; b < 2; ++b) acc[a][b] = (f32x4){0.f, 0.f, 0.f, 0.f};

  const _Float16* xb = xt + (size_t)nb * HWN * CC;
  const int j  = lane & 31;            // channel chunk j*8..j*8+7
  const int ph = lane >> 5;            // which pixel of the pair

  for (int k = 0; k < 9; ++k) {
    __syncthreads();   // prev tap A-reads done; (k==0) params visible

    // ---- sample tap k: 2 pixels per wave-iter, contiguous 512B row loads (R7-proven) ----
#pragma unroll
    for (int i = 0; i < 4; ++i) {
      int p = i * 16 + wv * 2 + ph;
      int idx = p * 9 + k;
      ushort4 o4 = s_po[idx];
      ushort4 hw4 = s_pw[idx];
      half2v w00 = u2h(dupu(hw4.x)), w01 = u2h(dupu(hw4.y));
      half2v w10 = u2h(dupu(hw4.z)), w11 = u2h(dupu(hw4.w));
      const _Float16* cb = xb + (size_t)j * 8;
      uint4 v00 = *(const uint4*)(cb + (size_t)o4.x * CC);
      uint4 v01 = *(const uint4*)(cb + (size_t)o4.y * CC);
      uint4 v10 = *(const uint4*)(cb + (size_t)o4.z * CC);
      uint4 v11 = *(const uint4*)(cb + (size_t)o4.w * CC);
      uint4 r;
      r.x = h2u(u2h(v00.x) * w00 + u2h(v01.x) * w01 + u2h(v10.x) * w10 + u2h(v11.x) * w11);
      r.y = h2u(u2h(v00.y) * w00 + u2h(v01.y) * w01 + u2h(v10.y) * w10 + u2h(v11.y) * w11);
      r.z = h2u(u2h(v00.z) * w00 + u2h(v01.z) * w01 + u2h(v10.z) * w10 + u2h(v11.z) * w11);
      r.w = h2u(u2h(v00.w) * w00 + u2h(v01.w) * w01 + u2h(v10.w) * w10 + u2h(v11.w) * w11);
      *(uint4*)(val_lds + p * VST + j * 8) = r;   // consecutive 16B per half-wave
    }

    // ---- GEMM tap k over four 64-channel chunks ----
    for (int cc = 0; cc < CC / KCH; ++cc) {
      __syncthreads();   // prev chunk B-reads done
      {
        // stage 256 o x 64 c = 32 KB: thread copies 32 halfs = 4 x uint4
        // (o,q): q=0 -> halfs 0..31, q=1 -> halfs 32..63 of row o
        int o = tid >> 1, q = tid & 1;
        const uint4* src = (const uint4*)(wt + ((size_t)(k * OO + o)) * CC + cc * KCH + q * 32);
        uint4* dst = (uint4*)(w_lds + o * WST + q * 32);
        dst[0] = src[0];
        dst[1] = src[1];
        dst[2] = src[2];
        dst[3] = src[3];
      }
      __syncthreads();   // w_lds staged; also orders val_lds writes before A-reads (cc==0)
#pragma unroll
      for (int ks = 0; ks < 2; ++ks) {
        int cbase = cc * KCH + ks * 32;
        half8 afr[4], bfr[2];
#pragma unroll
        for (int mt = 0; mt < 4; ++mt)
          afr[mt] = *(const half8*)(val_lds + (mt * 16 + n15) * VST + cbase + quad * 8);
#pragma unroll
        for (int nt = 0; nt < 2; ++nt)
          bfr[nt] = *(const half8*)(w_lds + (wv * 32 + nt * 16 + n15) * WST + ks * 32 + quad * 8);
#pragma unroll
        for (int mt = 0; mt < 4; ++mt)
#pragma unroll
          for (int nt = 0; nt < 2; ++nt)
            acc[mt][nt] = __builtin_amdgcn_mfma_f32_16x16x32_f16(
                afr[mt], bfr[nt], acc[mt][nt], 0, 0, 0);
      }
    }
  }

  // ---- epilogue: D: col=lane&15 -> o, row=quad*4+reg -> pixel ----
#pragma unroll
  for (int mt = 0; mt < 4; ++mt)
#pragma unroll
    for (int nt = 0; nt < 2; ++nt) {
      int o  = wv * 32 + nt * 16 + n15;
      int px = hw0 + mt * 16 + quad * 4;
      *(f32x4*)(out + ((size_t)nb * OO + o) * HWN + px) = acc[mt][nt];
    }
}

extern "C" void kernel_launch(void* const* d_in, const int* in_sizes, int n_in,
                              void* d_out, int out_size, void* d_ws, size_t ws_size,
                              hipStream_t stream) {
  const float* x   = (const float*)d_in[0];   // [4,256,64,64]
  const float* off = (const float*)d_in[1];   // [4,4096,18]
  const float* w   = (const float*)d_in[2];   // [256,256,3,3]
  float* out = (float*)d_out;                 // [4,256,64,64]

  _Float16* wt = (_Float16*)d_ws;             // 589824 fp16
  _Float16* xt = wt + 589824;                 // 4194304 fp16

  prep_kernel<<<1024 + 2304, 256, 0, stream>>>(x, w, xt, wt);
  deform_mfma_kernel<<<4 * HWN / MPB, 512, 0, stream>>>(xt, wt, off, out);
}